// Round 5
// baseline (1023.747 us; speedup 1.0000x reference)
//
#include <hip/hip_runtime.h>
#include <hip/hip_bf16.h>
#include <stdint.h>

using bf16 = __hip_bfloat16;
typedef __bf16 bf16x8 __attribute__((ext_vector_type(8)));
typedef float  f32x4  __attribute__((ext_vector_type(4)));

#define TOKENS 16384
#define DMODEL 1024
#define DFF    4096

// ---------------------------------------------------------------------------
// async global->LDS, 16B per lane. HW writes lane i at (uniform base)+i*16;
// our per-lane lds expressions equal base+lane*16 exactly (lane-ordered).
// ---------------------------------------------------------------------------
__device__ __forceinline__ void gload_lds16(const void* gptr, void* lptr) {
  __builtin_amdgcn_global_load_lds(
      (const __attribute__((address_space(1))) uint32_t*)gptr,
      (__attribute__((address_space(3))) uint32_t*)lptr,
      16, 0, 0);
}

__device__ __forceinline__ float bfraw2f(unsigned short u) {
  union { unsigned int i; float f; } x;
  x.i = ((unsigned int)u) << 16;
  return x.f;
}

__device__ __forceinline__ unsigned short f2bfraw(float f) {
  union { float f; unsigned int i; } x;
  x.f = f;
  unsigned int lsb = (x.i >> 16) & 1;
  return (unsigned short)((x.i + 0x7fff + lsb) >> 16);  // RNE (finite inputs)
}

// ---------------------------------------------------------------------------
// f32 -> bf16 elementwise convert (x). One float4 per thread.
// ---------------------------------------------------------------------------
__global__ __launch_bounds__(256) void cvt_f32_bf16(
    const float* __restrict__ in, bf16* __restrict__ out, int n4) {
  const int i = blockIdx.x * 256 + threadIdx.x;
  if (i >= n4) return;
  const float4 v = reinterpret_cast<const float4*>(in)[i];
  bf16 o[4] = {__float2bfloat16(v.x), __float2bfloat16(v.y),
               __float2bfloat16(v.z), __float2bfloat16(v.w)};
  reinterpret_cast<uint2*>(out)[i] = *reinterpret_cast<const uint2*>(o);
}

// ---------------------------------------------------------------------------
// Tiled transpose + convert: in[R][C] (f32) -> out[C][R] (bf16).
// ---------------------------------------------------------------------------
__global__ __launch_bounds__(256) void transpose_f32_bf16(
    const float* __restrict__ in, bf16* __restrict__ out, int R, int C) {
  __shared__ float tile[32][33];
  const int bx = blockIdx.x * 32;  // col base of input
  const int by = blockIdx.y * 32;  // row base of input
  const int tx = threadIdx.x;      // 0..31
  const int ty = threadIdx.y;      // 0..7
#pragma unroll
  for (int i = 0; i < 32; i += 8)
    tile[ty + i][tx] = in[(size_t)(by + ty + i) * C + (bx + tx)];
  __syncthreads();
#pragma unroll
  for (int i = 0; i < 32; i += 8)
    out[(size_t)(bx + ty + i) * R + (by + tx)] =
        __float2bfloat16(tile[tx][ty + i]);
}

// ---------------------------------------------------------------------------
// Wide GEMM: C[M,N] = A[M,K] * B[K,N] (+bias, +opt res/relu).
// A row-major bf16, Bt = B^T [N,K] row-major bf16.
// BM=128, BN=512, BK=32, 512 threads = 8 waves in 2(m)x4(n); each wave owns
// 64 rows x 128 cols = 4x8 mfma_f32_16x16x32_bf16 with SWAPPED operands:
// mfma(bfv, af) -> lane holds row = wm+mi*16+(lane&15),
//                  cols = wn+ni*16+(lane>>4)*4 + reg (4 consecutive cols).
// Epilogue: direct 8B stores (32B-aligned row segments, coalesces in TCC).
// epi: 0 = +bias; 1 = +bias,relu; 2 = +bias+resf(f32); 3 = +bias+resb(bf16)
// ---------------------------------------------------------------------------
__global__ __launch_bounds__(512) void gemm_wide(
    const bf16* __restrict__ A, const bf16* __restrict__ Bt,
    const float* __restrict__ bias, const float* __restrict__ resf,
    const bf16* __restrict__ resb, bf16* __restrict__ outb,
    const int M, const int N, const int K, const int epi) {
  __shared__ alignas(16) bf16 As[128 * 32];   //  8 KB
  __shared__ alignas(16) bf16 Bs[512 * 32];   // 32 KB

  const int t    = threadIdx.x;
  const int wave = t >> 6;
  const int lane = t & 63;
  const int m_base = blockIdx.y * 128;
  const int n_base = blockIdx.x * 512;
  const int wm = (wave >> 2) * 64;    // 0 or 64
  const int wn = (wave & 3) * 128;    // 0,128,256,384

  // staging: thread t covers A row t>>2 (one 16B chunk of the 64B row) and
  // B rows t>>2 (+128,+256,+384). LDS offset = t*16 (+ uniform chunk bases).
  const int sr = t >> 2;          // 0..127
  const int sk = (t & 3) * 8;     // k chunk
  const bf16* aptr  = A  + (size_t)(m_base + sr) * K + sk;
  const bf16* bptr  = Bt + (size_t)(n_base + sr) * K + sk;
  const size_t bstep = (size_t)128 * K;
  bf16* asp = &As[sr * 32 + sk];
  bf16* bsp = &Bs[sr * 32 + sk];

  const int lr = lane & 15;        // row within 16-tile
  const int lk = (lane >> 4) * 8;  // k offset within BK=32

  f32x4 acc[4][8] = {};

  for (int k0 = 0; k0 < K; k0 += 32) {
    gload_lds16(aptr + k0, asp);
    gload_lds16(bptr + k0, bsp);
    gload_lds16(bptr + bstep + k0, bsp + 128 * 32);
    gload_lds16(bptr + 2 * bstep + k0, bsp + 256 * 32);
    gload_lds16(bptr + 3 * bstep + k0, bsp + 384 * 32);
    __syncthreads();  // drains vmcnt -> LDS valid

    bf16x8 af[4], bfv[8];
#pragma unroll
    for (int i = 0; i < 4; ++i)
      af[i] = *reinterpret_cast<const bf16x8*>(&As[(wm + i * 16 + lr) * 32 + lk]);
#pragma unroll
    for (int j = 0; j < 8; ++j)
      bfv[j] = *reinterpret_cast<const bf16x8*>(&Bs[(wn + j * 16 + lr) * 32 + lk]);
#pragma unroll
    for (int mi = 0; mi < 4; ++mi)
#pragma unroll
      for (int ni = 0; ni < 8; ++ni)
        acc[mi][ni] = __builtin_amdgcn_mfma_f32_16x16x32_bf16(
            bfv[ni], af[mi], acc[mi][ni], 0, 0, 0);  // swapped -> row-major frag
    __syncthreads();  // protect LDS from next iteration's staging
  }

  // epilogue: lane owns rows wm+mi*16+lr, cols wn+ni*16+g4*4 .. +3
  const int g4 = lane >> 4;
#pragma unroll
  for (int ni = 0; ni < 8; ++ni) {
    const int col = n_base + wn + ni * 16 + g4 * 4;
    const float4 bv = *reinterpret_cast<const float4*>(&bias[col]);
#pragma unroll
    for (int mi = 0; mi < 4; ++mi) {
      const int row = m_base + wm + mi * 16 + lr;
      const size_t idx = (size_t)row * N + col;
      const f32x4 a = acc[mi][ni];
      float v0 = a[0] + bv.x, v1 = a[1] + bv.y;
      float v2 = a[2] + bv.z, v3 = a[3] + bv.w;
      if (epi == 1) {
        v0 = fmaxf(v0, 0.f); v1 = fmaxf(v1, 0.f);
        v2 = fmaxf(v2, 0.f); v3 = fmaxf(v3, 0.f);
      } else if (epi == 2) {
        const float4 r = *reinterpret_cast<const float4*>(&resf[idx]);
        v0 += r.x; v1 += r.y; v2 += r.z; v3 += r.w;
      } else if (epi == 3) {
        const uint2 rb = *reinterpret_cast<const uint2*>(&resb[idx]);
        v0 += bfraw2f((unsigned short)(rb.x & 0xffff));
        v1 += bfraw2f((unsigned short)(rb.x >> 16));
        v2 += bfraw2f((unsigned short)(rb.y & 0xffff));
        v3 += bfraw2f((unsigned short)(rb.y >> 16));
      }
      ushort4 pk = {f2bfraw(v0), f2bfraw(v1), f2bfraw(v2), f2bfraw(v3)};
      *reinterpret_cast<uint2*>(&outb[idx]) =
          *reinterpret_cast<const uint2*>(&pk);
    }
  }
}

// ---------------------------------------------------------------------------
// Per-token head-mixing attention. qkv row (3072): e = h*192 + which*64 + d,
// which: 0=q 1=k 2=v. scores[h][g] = q_h . k_g / 8, softmax over g,
// ctx[h*64+d] = sum_g p[h][g] * v[g][d].  One 256-thread block per token.
// ---------------------------------------------------------------------------
__global__ __launch_bounds__(256) void attn_kernel(
    const bf16* __restrict__ qkv, bf16* __restrict__ ctx) {
  __shared__ float q[16][65], kk[16][65], vv[16][65];
  __shared__ float sc[16][17], pw[16][17];
  const int tok = blockIdx.x;
  const int t   = threadIdx.x;

  const ushort2* base2 =
      reinterpret_cast<const ushort2*>(qkv + (size_t)tok * 3072);
#pragma unroll
  for (int e2 = t; e2 < 1536; e2 += 256) {
    const ushort2 u = base2[e2];
    const int e = e2 * 2;
    const int h = e / 192;
    const int rem = e - h * 192;
    const int which = rem >> 6;
    const int d = rem & 63;
    const float f0 = bfraw2f(u.x), f1 = bfraw2f(u.y);
    if (which == 0)      { q[h][d] = f0;  q[h][d + 1] = f1; }
    else if (which == 1) { kk[h][d] = f0; kk[h][d + 1] = f1; }
    else                 { vv[h][d] = f0; vv[h][d + 1] = f1; }
  }
  __syncthreads();

  const int h = t >> 4, g = t & 15;
  float s = 0.f;
#pragma unroll
  for (int d = 0; d < 64; ++d) s += q[h][d] * kk[g][d];
  s *= 0.125f;
  sc[h][g] = s;
  __syncthreads();

  float mx = sc[h][0];
#pragma unroll
  for (int j = 1; j < 16; ++j) mx = fmaxf(mx, sc[h][j]);
  float sum = 0.f;
#pragma unroll
  for (int j = 0; j < 16; ++j) sum += __expf(sc[h][j] - mx);
  pw[h][g] = __expf(s - mx) / sum;
  __syncthreads();

  const int d0 = (t & 15) * 4;
  float c0 = 0.f, c1 = 0.f, c2 = 0.f, c3 = 0.f;
#pragma unroll
  for (int j = 0; j < 16; ++j) {
    const float w = pw[h][j];
    c0 += w * vv[j][d0 + 0];
    c1 += w * vv[j][d0 + 1];
    c2 += w * vv[j][d0 + 2];
    c3 += w * vv[j][d0 + 3];
  }
  bf16 o[4] = {__float2bfloat16(c0), __float2bfloat16(c1),
               __float2bfloat16(c2), __float2bfloat16(c3)};
  *reinterpret_cast<uint2*>(ctx + (size_t)tok * 1024 + t * 4) =
      *reinterpret_cast<const uint2*>(o);
}

// ---------------------------------------------------------------------------
// LayerNorm over 1024, bf16 input, f32 gamma/beta.
// outf != nullptr: write f32. else write bf16 to outb.
// One block per row, 256 threads x 4 elements.
// ---------------------------------------------------------------------------
__global__ __launch_bounds__(256) void ln_kernel(
    const bf16* __restrict__ y, const float* __restrict__ gamma,
    const float* __restrict__ beta, bf16* __restrict__ outb,
    float* __restrict__ outf) {
  const int row = blockIdx.x;
  const int t = threadIdx.x;
  const uint2 raw =
      reinterpret_cast<const uint2*>(y + (size_t)row * 1024)[t];
  float f0 = bfraw2f((unsigned short)(raw.x & 0xffff));
  float f1 = bfraw2f((unsigned short)(raw.x >> 16));
  float f2 = bfraw2f((unsigned short)(raw.y & 0xffff));
  float f3 = bfraw2f((unsigned short)(raw.y >> 16));
  float s  = f0 + f1 + f2 + f3;
  float ss = f0 * f0 + f1 * f1 + f2 * f2 + f3 * f3;
#pragma unroll
  for (int off = 32; off > 0; off >>= 1) {
    s  += __shfl_down(s, off);
    ss += __shfl_down(ss, off);
  }
  __shared__ float red[8];
  const int wave = t >> 6, lane = t & 63;
  if (lane == 0) { red[wave] = s; red[wave + 4] = ss; }
  __syncthreads();
  s  = red[0] + red[1] + red[2] + red[3];
  ss = red[4] + red[5] + red[6] + red[7];
  const float mu  = s * (1.0f / 1024.0f);
  const float var = ss * (1.0f / 1024.0f) - mu * mu;
  const float inv = rsqrtf(var + 1e-5f);
  const int c = t * 4;
  const float r0 = (f0 - mu) * inv * gamma[c + 0] + beta[c + 0];
  const float r1 = (f1 - mu) * inv * gamma[c + 1] + beta[c + 1];
  const float r2 = (f2 - mu) * inv * gamma[c + 2] + beta[c + 2];
  const float r3 = (f3 - mu) * inv * gamma[c + 3] + beta[c + 3];
  if (outf != nullptr) {
    float4 o4 = {r0, r1, r2, r3};
    reinterpret_cast<float4*>(outf + (size_t)row * 1024)[t] = o4;
  } else {
    bf16 o[4] = {__float2bfloat16(r0), __float2bfloat16(r1),
                 __float2bfloat16(r2), __float2bfloat16(r3)};
    *reinterpret_cast<uint2*>(outb + (size_t)row * 1024 + c) =
        *reinterpret_cast<const uint2*>(o);
  }
}

// ---------------------------------------------------------------------------
extern "C" void kernel_launch(void* const* d_in, const int* in_sizes, int n_in,
                              void* d_out, int out_size, void* d_ws, size_t ws_size,
                              hipStream_t stream) {
  const float* x    = (const float*)d_in[0];
  const float* Wqkv = (const float*)d_in[1];
  const float* bqkv = (const float*)d_in[2];
  const float* Wo   = (const float*)d_in[3];
  const float* bo   = (const float*)d_in[4];
  const float* W1   = (const float*)d_in[5];
  const float* b1   = (const float*)d_in[6];
  const float* W2   = (const float*)d_in[7];
  const float* b2   = (const float*)d_in[8];
  const float* g1   = (const float*)d_in[9];
  const float* be1  = (const float*)d_in[10];
  const float* g2   = (const float*)d_in[11];
  const float* be2  = (const float*)d_in[12];
  float* out = (float*)d_out;  // reference output dtype is float32

  // Workspace layout (overlays annotated). Total ~226 MB.
  //  A (33.5MB): xb -> ctx -> y2b
  //  B (134.2MB): qkvb(100.7) ++ ybufb(33.5); hbuf = whole region
  //  D (33.5MB): x1b
  //  E (25.2MB): transposed weights
  char* p = (char*)d_ws;
  bf16* regA  = (bf16*)p;  p += (size_t)TOKENS * 1024 * 2;
  bf16* qkvb  = (bf16*)p;  // also start of hbuf
  bf16* hbuf  = qkvb;
  p += (size_t)TOKENS * 3072 * 2;
  bf16* ybufb = (bf16*)p;  p += (size_t)TOKENS * 1024 * 2;
  bf16* x1b   = (bf16*)p;  p += (size_t)TOKENS * 1024 * 2;
  bf16* WqkvT = (bf16*)p;  p += (size_t)3072 * 1024 * 2;
  bf16* WoT   = (bf16*)p;  p += (size_t)1024 * 1024 * 2;
  bf16* W1T   = (bf16*)p;  p += (size_t)4096 * 1024 * 2;
  bf16* W2T   = (bf16*)p;  p += (size_t)1024 * 4096 * 2;

  bf16* xb  = regA;   // x as bf16 (dead after QKV GEMM)
  bf16* ctx = regA;   // attn output (dead after Wo GEMM)
  bf16* y2b = regA;   // FF2 output pre-LN

  // x -> bf16
  cvt_f32_bf16<<<(TOKENS * 1024 / 4 + 255) / 256, 256, 0, stream>>>(
      x, xb, TOKENS * 1024 / 4);

  // weight transposes + convert: W[K][N] f32 -> Wt[N][K] bf16
  const dim3 tb(32, 8);
  transpose_f32_bf16<<<dim3(3072 / 32, 1024 / 32), tb, 0, stream>>>(Wqkv, WqkvT, 1024, 3072);
  transpose_f32_bf16<<<dim3(1024 / 32, 1024 / 32), tb, 0, stream>>>(Wo,   WoT,   1024, 1024);
  transpose_f32_bf16<<<dim3(4096 / 32, 1024 / 32), tb, 0, stream>>>(W1,   W1T,   1024, 4096);
  transpose_f32_bf16<<<dim3(1024 / 32, 4096 / 32), tb, 0, stream>>>(W2,   W2T,   4096, 1024);

  // qkv = x @ Wqkv + bqkv -> bf16
  gemm_wide<<<dim3(3072 / 512, TOKENS / 128), 512, 0, stream>>>(
      xb, WqkvT, bqkv, nullptr, nullptr, qkvb, TOKENS, 3072, 1024, 0);

  // per-token attention -> ctx bf16 (overwrites xb)
  attn_kernel<<<TOKENS, 256, 0, stream>>>(qkvb, ctx);

  // y = ctx @ Wo + bo + x -> bf16 (into ybufb)
  gemm_wide<<<dim3(1024 / 512, TOKENS / 128), 512, 0, stream>>>(
      ctx, WoT, bo, x, nullptr, ybufb, TOKENS, 1024, 1024, 2);

  // x1 = LN(y) -> bf16
  ln_kernel<<<TOKENS, 256, 0, stream>>>(ybufb, g1, be1, x1b, nullptr);

  // h = relu(x1 @ W1 + b1) -> bf16 (overlays qkvb+ybufb, both dead)
  gemm_wide<<<dim3(4096 / 512, TOKENS / 128), 512, 0, stream>>>(
      x1b, W1T, b1, nullptr, nullptr, hbuf, TOKENS, 4096, 1024, 1);

  // y2 = h @ W2 + b2 + x1 -> bf16 (into region A, ctx dead)
  gemm_wide<<<dim3(1024 / 512, TOKENS / 128), 512, 0, stream>>>(
      hbuf, W2T, b2, nullptr, x1b, y2b, TOKENS, 1024, 4096, 3);

  // out = LN(y2) -> f32 (harness output dtype)
  ln_kernel<<<TOKENS, 256, 0, stream>>>(y2b, g2, be2, nullptr, out);
}